// Round 20
// baseline (295.743 us; speedup 1.0000x reference)
//
#include <hip/hip_runtime.h>
#include <math.h>

#define IMG_H 512
#define IMG_W 512
#define N_IMG 96            // 32 * 3
#define TW 32               // tile width (output cols)
#define TH 128              // tile height (output rows)
#define KS 11
#define IN_ROWS 138         // TH + 10
#define NUNITS (IN_ROWS * 8)    // 1104 horizontal-conv units (4 px each)
#define STRIDE 33           // LDS row stride in float2 units
#define PLANE (IN_ROWS * STRIDE)   // 4554 float2
#define GRID 512            // exactly 2 blocks/CU resident (r18: co-schedulable)
#define NSTRIPS 1536        // 96 images * 16 column strips
#define TILES_Y 4           // 512 / TH
#define TOTAL_N 25165824.0  // 32*3*512*512

// Round-19 (resubmit; infra failure): PERSISTENT 2-blocks/CU. r17/r18:
// waves-resident is the binding resource (512thr->59% occ/124us,
// 1024thr->65%/117us; true VALU ~33%, all pipes <31%). Occupancy loss =
// block-boundary drain/fill gaps (24 slots/CU).
// Fix: grid=512 = exactly 2x1024-thr blocks per CU (PROVEN co-residency at
// r18's LDS 73.2KBx2=146.4<160KB), each persistent over 12 tile-tasks
// (3 column strips x 4 vertical tiles). Steady 32 waves/CU; block A's
// stage-1 HBM stall overlaps block B's compute.
// CRITICAL: VGPR must stay <=64 for 2-block residency -> (1024,8) caps at
// 64; kernel measured 32 (r18). Tripwire: WRITE_SIZE >> 1MB = spill -> revert.
// Internals byte-identical to r18 (u/v 4-map, gather-then-convolve,
// stride-33 float2 planes, ~0 conflicts).

#define GW(j) g6[(j) <= 5 ? (j) : 10 - (j)]

__global__ __launch_bounds__(1024, 8) void ssim_tile_kernel(
    const float* __restrict__ pred, const float* __restrict__ targ,
    const float* __restrict__ k2d, float* __restrict__ partial)
{
    __shared__ float2 Hu[PLANE];
    __shared__ float2 Hv[PLANE];
    __shared__ float wsum[16];

    const int tid = threadIdx.x;
    const int bid = blockIdx.x;

    // exact 1D gaussian from the 2D kernel row 5: k2d[5][j] = g5*g[j]; symmetric
    float g6[6];
    {
        const float inv = rsqrtf(k2d[5 * KS + 5]);
        #pragma unroll
        for (int j = 0; j < 6; ++j) g6[j] = k2d[5 * KS + j] * inv;
    }

    const float C1 = 1.0e-4f;   // (0.01*1)^2
    const float C2 = 9.0e-4f;   // (0.03*1)^2
    float acc = 0.0f;           // per-thread SSIM sum across all 12 tiles

    #pragma unroll
    for (int s = 0; s < 3; ++s) {
        const int sid = bid + (s << 9);        // strip id 0..1535
        const int img = sid >> 4;
        const int tx  = sid & 15;
        const int x0  = tx * TW;
        const float* __restrict__ Pimg = pred + (size_t)img * (IMG_H * IMG_W);
        const float* __restrict__ Timg = targ + (size_t)img * (IMG_H * IMG_W);

        for (int ty = 0; ty < TILES_Y; ++ty) {
            const int y0 = ty * TH;

            // ---- stage 1: horizontal 11-tap on u,v,u^2,v^2 -> LDS planes ----
            #pragma unroll
            for (int b = 0; b < 2; ++b) {
                const int u = tid + (b << 10);     // b=0: all 1024; b=1: tid<80
                if (u < NUNITS) {
                    const int r    = u >> 3;       // 0..137
                    const int cg   = u & 7;        // 0..7
                    const int gr   = y0 - 5 + r;
                    const int col0 = x0 + (cg << 2) - 8;   // 16B-aligned
                    const bool rowok = ((unsigned)gr < (unsigned)IMG_H);
                    const float* rowP = Pimg + (size_t)(rowok ? gr : 0) * IMG_W;
                    const float* rowT = Timg + (size_t)(rowok ? gr : 0) * IMG_W;

                    // used window elems are 3..16 -> uw/vw[0..13]
                    float uw[14], vw[14];
                    if (rowok && col0 >= 0 && col0 + 20 <= IMG_W) {
                        #pragma unroll
                        for (int q = 0; q < 5; ++q) {
                            const float4 vp = *(const float4*)(rowP + col0 + 4 * q);
                            const float4 vt = *(const float4*)(rowT + col0 + 4 * q);
                            const float pe[4] = {vp.x, vp.y, vp.z, vp.w};
                            const float te[4] = {vt.x, vt.y, vt.z, vt.w};
                            #pragma unroll
                            for (int e = 0; e < 4; ++e) {
                                const int ge = 4 * q + e;      // compile-time
                                if (ge >= 3 && ge <= 16) {
                                    uw[ge - 3] = pe[e] + te[e];
                                    vw[ge - 3] = pe[e] - te[e];
                                }
                            }
                        }
                    } else {
                        #pragma unroll
                        for (int e = 3; e <= 16; ++e) {
                            const int c  = col0 + e;
                            const int cc = min(max(c, 0), IMG_W - 1);
                            const bool ok = rowok && (c >= 0) && (c < IMG_W);
                            const float pv = rowP[cc];
                            const float tv = rowT[cc];
                            uw[e - 3] = ok ? (pv + tv) : 0.0f;
                            vw[e - 3] = ok ? (pv - tv) : 0.0f;
                        }
                    }

                    const int wb = r * STRIDE + (cg << 2);

                    // u-maps
                    {
                        float au[4], auu[4];
                        #pragma unroll
                        for (int k = 0; k < 4; ++k) { au[k] = 0.f; }
                        #pragma unroll
                        for (int k = 0; k < 4; ++k) {
                            #pragma unroll
                            for (int j = 0; j < KS; ++j)
                                au[k] = fmaf(GW(j), uw[k + j], au[k]);
                        }
                        #pragma unroll
                        for (int i = 0; i < 14; ++i) uw[i] *= uw[i];
                        #pragma unroll
                        for (int k = 0; k < 4; ++k) { auu[k] = 0.f; }
                        #pragma unroll
                        for (int k = 0; k < 4; ++k) {
                            #pragma unroll
                            for (int j = 0; j < KS; ++j)
                                auu[k] = fmaf(GW(j), uw[k + j], auu[k]);
                        }
                        #pragma unroll
                        for (int e = 0; e < 4; ++e)
                            Hu[wb + e] = make_float2(au[e], auu[e]);
                    }
                    // v-maps
                    {
                        float av[4], avv[4];
                        #pragma unroll
                        for (int k = 0; k < 4; ++k) { av[k] = 0.f; }
                        #pragma unroll
                        for (int k = 0; k < 4; ++k) {
                            #pragma unroll
                            for (int j = 0; j < KS; ++j)
                                av[k] = fmaf(GW(j), vw[k + j], av[k]);
                        }
                        #pragma unroll
                        for (int i = 0; i < 14; ++i) vw[i] *= vw[i];
                        #pragma unroll
                        for (int k = 0; k < 4; ++k) { avv[k] = 0.f; }
                        #pragma unroll
                        for (int k = 0; k < 4; ++k) {
                            #pragma unroll
                            for (int j = 0; j < KS; ++j)
                                avv[k] = fmaf(GW(j), vw[k + j], avv[k]);
                        }
                        #pragma unroll
                        for (int e = 0; e < 4; ++e)
                            Hv[wb + e] = make_float2(av[e], avv[e]);
                    }
                }
            }
            __syncthreads();

            // ---- stage 2: vertical 11-tap (streaming from LDS) + SSIM ----
            {
                const int col = tid & 31;
                const int rg  = tid >> 5;      // 0..31, rows rg*4 .. rg*4+3

                float sau[4], sav[4], sauu[4], savv[4];
                #pragma unroll
                for (int k = 0; k < 4; ++k) {
                    sau[k] = 0.f; sav[k] = 0.f; sauu[k] = 0.f; savv[k] = 0.f;
                }

                #pragma unroll
                for (int i = 0; i < 14; ++i) {
                    const int idx = (rg * 4 + i) * STRIDE + col;
                    const float2 hu = Hu[idx];
                    const float2 hv = Hv[idx];
                    #pragma unroll
                    for (int k = 0; k < 4; ++k) {
                        const int j = i - k;           // compile-time tap
                        if (j >= 0 && j < KS) {
                            sau [k] = fmaf(GW(j), hu.x, sau [k]);
                            sauu[k] = fmaf(GW(j), hu.y, sauu[k]);
                            sav [k] = fmaf(GW(j), hv.x, sav [k]);
                            savv[k] = fmaf(GW(j), hv.y, savv[k]);
                        }
                    }
                }

                #pragma unroll
                for (int k = 0; k < 4; ++k) {
                    const float u2 = sau[k] * sau[k];   // muu^2
                    const float v2 = sav[k] * sav[k];   // muv^2
                    const float A  = u2 - v2;           // 4*mux*muy
                    const float B  = u2 + v2;           // 2*(mux^2+muy^2)
                    const float Cd = sauu[k] - savv[k]; // 4*conv(xy)
                    const float Cs = sauu[k] + savv[k]; // 2*(conv(x2)+conv(y2))
                    const float num1 = fmaf(0.5f, A, C1);
                    const float den1 = fmaf(0.5f, B, C1);
                    const float num2 = fmaf(0.5f, Cd - A, C2);
                    const float den2 = fmaf(0.5f, Cs - B, C2);
                    acc = fmaf(num1 * num2, __builtin_amdgcn_rcpf(den1 * den2), acc);
                }
            }
            __syncthreads();   // protect H planes before next tile's stage 1
        }
    }

    // ---- block reduction (16 waves, once) ----
    #pragma unroll
    for (int off = 32; off > 0; off >>= 1)
        acc += __shfl_down(acc, off, 64);

    const int lane = tid & 63;
    const int wid  = tid >> 6;         // 0..15
    if (lane == 0) wsum[wid] = acc;
    __syncthreads();
    if (tid == 0) {
        float s = 0.0f;
        #pragma unroll
        for (int w = 0; w < 16; ++w) s += wsum[w];
        partial[bid] = s;
    }
}

// ---------------- final reduction ----------------
__global__ __launch_bounds__(1024) void ssim_reduce_kernel(
    const float* __restrict__ partial, int n, float* __restrict__ out)
{
    const int tid = threadIdx.x;
    double s = 0.0;
    for (int i = tid; i < n; i += 1024) s += (double)partial[i];

    #pragma unroll
    for (int off = 32; off > 0; off >>= 1)
        s += __shfl_down(s, off, 64);

    __shared__ double dsum[16];
    const int lane = tid & 63;
    const int wid  = tid >> 6;
    if (lane == 0) dsum[wid] = s;
    __syncthreads();
    if (tid == 0) {
        double total = 0.0;
        #pragma unroll
        for (int w = 0; w < 16; ++w) total += dsum[w];
        out[0] = (float)(1.0 - total / TOTAL_N);
    }
}

extern "C" void kernel_launch(void* const* d_in, const int* in_sizes, int n_in,
                              void* d_out, int out_size, void* d_ws, size_t ws_size,
                              hipStream_t stream) {
    const float* pred = (const float*)d_in[0];
    const float* targ = (const float*)d_in[1];
    const float* k2d  = (const float*)d_in[2];
    float* out = (float*)d_out;
    float* ws  = (float*)d_ws;   // GRID partial sums

    ssim_tile_kernel<<<GRID, 1024, 0, stream>>>(pred, targ, k2d, ws);
    ssim_reduce_kernel<<<1, 1024, 0, stream>>>(ws, GRID, out);
}